// Round 4
// baseline (59387.445 us; speedup 1.0000x reference)
//
#include <hip/hip_runtime.h>
#include <stdint.h>
#include <math.h>

#define NN 1024
#define NB 16
#define NLOW 16
#define PNB 32      // panel width
#define JCH 256     // symv col-chunk

// ---------------------------------------------------------------------------
// M = 0.5*(A + A^T). Safe when A == M (each (r<=c) pair owned by one thread).
__global__ void k_symmetrize(const float* A, float* M) {
    int64_t t = (int64_t)blockIdx.x * blockDim.x + threadIdx.x;
    if (t >= (int64_t)NB * NN * NN) return;
    int b = (int)(t / (NN * NN));
    int rc = (int)(t % (NN * NN));
    int r = rc / NN, c = rc % NN;
    if (r > c) return;
    const float* Ab = A + (int64_t)b * NN * NN;
    float s = 0.5f * (Ab[(int64_t)r * NN + c] + Ab[(int64_t)c * NN + r]);
    float* Mb = M + (int64_t)b * NN * NN;
    Mb[(int64_t)r * NN + c] = s;
    Mb[(int64_t)c * NN + r] = s;
}

__global__ void k_zeroinit(float* wv) {
    int t = blockIdx.x * 256 + threadIdx.x;
    if (t < NB * NN) wv[t] = 0.f;
}

// ---------------------------------------------------------------------------
// Fused per-column kernel: one block per batch, 1024 threads.
// Phase A (j>0): finalize W col j-1 = taut*(wraw - corrections); dotw (block red).
// Phase B (do_col): column update (rank-2j on the fly) -> unscaled reflector u;
//   norm2 block-reduce; scalars beta/taut/albe; write u to Vp, M col k, Urev.
// Phase C (do_col): dots c1[t]=w'_t^T u_j, c2[t]=u_t^T u_j for t<j (wave each).
__global__ __launch_bounds__(1024) void k_mid(float* M, float* Vp, float* Wp, float* wv,
                                              float* tauA, float* eA, float* dA,
                                              double* dotwA, double* c1A, double* c2A,
                                              float* Urev, int useU,
                                              int k0, int j, int do_col) {
    int b = blockIdx.x, tid = threadIdx.x;
    int wid = tid >> 6, lane = tid & 63;
    int m0 = NN - 1 - k0;
    float* Mb = M + (int64_t)b * NN * NN;
    __shared__ double sred[16];
    __shared__ float g1[PNB], g2[PNB], h1[PNB], h2[PNB], h3[PNB];
    __shared__ float shu[NN];
    __shared__ float sc_alpha, sc_albe;

    if (j > 0) {
        int jp = j - 1, kp = k0 + jp;
        if (tid < jp) {
            double kap = 0.5 * (double)tauA[b * NN + k0 + tid] * dotwA[b * NN + k0 + tid];
            double c2 = c2A[b * PNB + tid];
            g1[tid] = (float)(c1A[b * PNB + tid] - 2.0 * kap * c2);
            g2[tid] = (float)c2;
        }
        __syncthreads();
        float taut = tauA[b * NN + kp];
        const float* ujp = Vp + ((int64_t)b * PNB + jp) * NN;
        float* wcol = Wp + ((int64_t)b * PNB + jp) * NN;
        int i = jp + tid;
        double dacc = 0.0;
        if (i < m0) {
            float wr = wv[b * NN + i];
            wv[b * NN + i] = 0.f;
            for (int t = 0; t < jp; ++t)
                wr -= Vp[((int64_t)b * PNB + t) * NN + i] * g1[t]
                    + Wp[((int64_t)b * PNB + t) * NN + i] * g2[t];
            float wf = taut * wr;
            wcol[i] = wf;
            dacc = (double)wf * (double)ujp[i];
        }
        for (int o = 32; o; o >>= 1) dacc += __shfl_xor(dacc, o);
        if (lane == 0) sred[wid] = dacc;
        __syncthreads();
        if (tid == 0) {
            double tot = 0.0;
            for (int w = 0; w < 16; ++w) tot += sred[w];
            dotwA[b * NN + kp] = tot;
        }
        __syncthreads();
    }

    if (!do_col) return;

    int k = k0 + j;
    if (tid < j) {
        int r = j - 1;
        float ur = Vp[((int64_t)b * PNB + tid) * NN + r];
        float wr = Wp[((int64_t)b * PNB + tid) * NN + r];
        float kap = (float)(0.5 * (double)tauA[b * NN + k0 + tid] * dotwA[b * NN + k0 + tid]);
        float wbar = wr - kap * ur;
        h1[tid] = wbar - kap * ur;
        h2[tid] = ur;
        h3[tid] = ur * wbar;
    }
    __syncthreads();
    int i = j + tid;
    float x = 0.f;
    if (i < m0) {
        x = Mb[(int64_t)(k0 + 1 + i) * NN + k];
        for (int t = 0; t < j; ++t)
            x -= Vp[((int64_t)b * PNB + t) * NN + i] * h1[t]
               + Wp[((int64_t)b * PNB + t) * NN + i] * h2[t];
    }
    if (tid == 0) sc_alpha = x;
    double nacc = (i > j && i < m0) ? (double)x * (double)x : 0.0;
    for (int o = 32; o; o >>= 1) nacc += __shfl_xor(nacc, o);
    if (lane == 0) sred[wid] = nacc;
    __syncthreads();
    if (tid == 0) {
        double rest = 0.0;
        for (int w = 0; w < 16; ++w) rest += sred[w];
        float albe, beta, taut;
        if (rest == 0.0) { albe = 0.f; beta = sc_alpha; taut = 0.f; }
        else {
            double a = (double)sc_alpha;
            double nrm = sqrt(a * a + rest);
            double bt = (a >= 0.0) ? -nrm : nrm;
            double ab = a - bt;
            albe = (float)ab;
            beta = (float)bt;
            taut = (float)(-1.0 / (bt * ab));
        }
        float dk = Mb[(int64_t)k * NN + k];
        for (int t = 0; t < j; ++t) dk -= 2.f * h3[t];
        dA[b * NN + k] = dk;
        tauA[b * NN + k] = taut;
        eA[b * NN + k] = beta;
        sc_albe = albe;
    }
    __syncthreads();
    if (i < m0) {
        float val = (tid == 0) ? sc_albe : x;
        Vp[((int64_t)b * PNB + j) * NN + i] = val;
        Mb[(int64_t)(k0 + 1 + i) * NN + k] = val;
        if (useU) Urev[((int64_t)b * NN + k) * NN + (i - j)] = val;
        shu[i] = val;
    }
    __syncthreads();
    for (int t = wid; t < j; t += 16) {
        const float* ut = Vp + ((int64_t)b * PNB + t) * NN;
        const float* wt = Wp + ((int64_t)b * PNB + t) * NN;
        double a1 = 0.0, a2 = 0.0;
        for (int i2 = j + lane; i2 < m0; i2 += 64) {
            float uj = shu[i2];
            a1 += (double)wt[i2] * (double)uj;
            a2 += (double)ut[i2] * (double)uj;
        }
        for (int o = 32; o; o >>= 1) { a1 += __shfl_xor(a1, o); a2 += __shfl_xor(a2, o); }
        if (lane == 0) { c1A[b * PNB + t] = a1; c2A[b * PNB + t] = a2; }
    }
}

// ---------------------------------------------------------------------------
// Pure matvec: wraw += A(k+1:,k+1:) * u_j (panel-start matrix), atomics.
__global__ __launch_bounds__(256) void k_symv(const float* M, const float* Vp, float* wv,
                                              int k0, int j) {
    int b = blockIdx.x;
    int k = k0 + j, m = NN - 1 - k, base = k + 1;
    int i = blockIdx.y * 256 + threadIdx.x;
    int jg0 = blockIdx.z * JCH;
    int jg1 = min(m, jg0 + JCH);
    __shared__ float vs[JCH];
    const float* vcol = Vp + ((int64_t)b * PNB + j) * NN;
    for (int t = threadIdx.x; t < jg1 - jg0; t += 256) vs[t] = vcol[jg0 + t + j];
    __syncthreads();
    if (i >= m) return;
    const float* Mb = M + (int64_t)b * NN * NN;
    const float* p = Mb + (int64_t)(base + jg0) * NN + base + i;
    float acc = 0.f;
    for (int jg = jg0; jg < jg1; ++jg, p += NN) acc += (*p) * vs[jg - jg0];
    atomicAdd(&wv[b * NN + i + j], acc);
}

// ---------------------------------------------------------------------------
// Trailing update A(s:,s:) -= U*Wbar^T + Wbar*U^T with Wbar = w' - kappa*u.
__global__ __launch_bounds__(256) void k_update(float* M, const float* Vp, const float* Wp,
                                                const float* tauA, const double* dotwA,
                                                int k0, int nbe) {
    int b = blockIdx.x;
    int s = k0 + nbe, m2 = NN - s;
    int r0 = blockIdx.y * 64, c0 = blockIdx.z * 64;
    if (r0 >= m2 || c0 >= m2) return;
    __shared__ float Vr[PNB][64], Wr[PNB][64], Vc[PNB][64], Wc[PNB][64];
    __shared__ float kap[PNB];
    int tid = threadIdx.x;
    if (tid < nbe)
        kap[tid] = (float)(0.5 * (double)tauA[b * NN + k0 + tid] * dotwA[b * NN + k0 + tid]);
    __syncthreads();
    int rowoff = nbe - 1;
    for (int idx = tid; idx < nbe * 64; idx += 256) {
        int t = idx >> 6, x = idx & 63;
        const float* vp = Vp + ((int64_t)b * PNB + t) * NN;
        const float* wp = Wp + ((int64_t)b * PNB + t) * NN;
        int rr = r0 + x, cc = c0 + x;
        float vr = (rr < m2) ? vp[rowoff + rr] : 0.f;
        float wr = (rr < m2) ? wp[rowoff + rr] : 0.f;
        float vc = (cc < m2) ? vp[rowoff + cc] : 0.f;
        float wc = (cc < m2) ? wp[rowoff + cc] : 0.f;
        Vr[t][x] = vr; Wr[t][x] = wr - kap[t] * vr;
        Vc[t][x] = vc; Wc[t][x] = wc - kap[t] * vc;
    }
    __syncthreads();
    int tx = tid & 15, ty = tid >> 4;
    float accv[4][4] = {};
    for (int t = 0; t < nbe; ++t) {
        float va[4], wa[4], vb4[4], wb4[4];
#pragma unroll
        for (int a = 0; a < 4; ++a) {
            va[a] = Vr[t][ty * 4 + a]; wa[a] = Wr[t][ty * 4 + a];
            vb4[a] = Vc[t][tx * 4 + a]; wb4[a] = Wc[t][tx * 4 + a];
        }
#pragma unroll
        for (int a = 0; a < 4; ++a)
#pragma unroll
            for (int c = 0; c < 4; ++c) accv[a][c] += va[a] * wb4[c] + wa[a] * vb4[c];
    }
    float* Mb = M + (int64_t)b * NN * NN;
    for (int a = 0; a < 4; ++a) {
        int r = r0 + ty * 4 + a;
        if (r >= m2) break;
        for (int c = 0; c < 4; ++c) {
            int cc = c0 + tx * 4 + c;
            if (cc >= m2) continue;
            Mb[(int64_t)(s + r) * NN + (s + cc)] -= accv[a][c];
        }
    }
}

// ---------------------------------------------------------------------------
__global__ void k_extract2(const float* M, float* dA, float* eA) {
    int b = blockIdx.x;
    if (threadIdx.x == 0) {
        const float* Mb = M + (int64_t)b * NN * NN;
        dA[b * NN + NN - 2] = Mb[(int64_t)(NN - 2) * NN + NN - 2];
        dA[b * NN + NN - 1] = Mb[(int64_t)(NN - 1) * NN + NN - 1];
        eA[b * NN + NN - 2] = Mb[(int64_t)(NN - 1) * NN + NN - 2];
    }
}

// ---------------------------------------------------------------------------
__global__ void k_bisect(const float* dA, const float* eA, double* lam, float* out) {
    int p = threadIdx.x;
    int b = p >> 4, j = p & 15;
    const float* d = dA + b * NN;
    const float* e = eA + b * NN;
    double lo = 1e30, hi = -1e30;
    for (int i = 0; i < NN; ++i) {
        double di = (double)d[i];
        double r = 0.0;
        if (i > 0) r += fabs((double)e[i - 1]);
        if (i < NN - 1) r += fabs((double)e[i]);
        lo = fmin(lo, di - r);
        hi = fmax(hi, di + r);
    }
    lo -= 1e-3; hi += 1e-3;
    for (int it = 0; it < 50; ++it) {
        double x = 0.5 * (lo + hi);
        int cnt = 0;
        double q = (double)d[0] - x;
        if (q < 0.0) cnt++;
        for (int i = 1; i < NN; ++i) {
            double ei = (double)e[i - 1];
            double den = q;
            if (fabs(den) < 1e-30) den = (den < 0.0) ? -1e-30 : 1e-30;
            q = ((double)d[i] - x) - ei * ei / den;
            if (q < 0.0) cnt++;
        }
        if (cnt >= j + 1) hi = x; else lo = x;
    }
    double l = 0.5 * (lo + hi);
    lam[p] = l;
    out[b * NLOW + j] = (float)l;
}

// ---------------------------------------------------------------------------
__global__ void k_invit(const float* dA, const float* eA, const double* lam,
                        float* vtri, double* U0, double* U1, double* U2,
                        double* LM, float* PV, double* XV) {
    int p = blockIdx.x * blockDim.x + threadIdx.x;
    if (p >= NB * NLOW) return;
    int b = p / NLOW;
    const float* d = dA + b * NN;
    const float* e = eA + b * NN;
    double lambda = lam[p];
    double* dd  = U0 + (int64_t)p * NN;
    double* du  = U1 + (int64_t)p * NN;
    double* du2 = U2 + (int64_t)p * NN;
    double* dl  = LM + (int64_t)p * NN;
    float*  pv  = PV + (int64_t)p * NN;
    double* X   = XV + (int64_t)p * NN;

    for (int i = 0; i < NN; ++i) dd[i] = (double)d[i] - lambda;
    for (int i = 0; i < NN - 1; ++i) { du[i] = (double)e[i]; dl[i] = (double)e[i]; }
    du[NN - 1] = 0.0; dl[NN - 1] = 0.0;

    for (int i = 0; i < NN - 1; ++i) {
        if (fabs(dd[i]) >= fabs(dl[i])) {
            pv[i] = 0.f;
            double fact = (dd[i] != 0.0) ? dl[i] / dd[i] : 0.0;
            dl[i] = fact;
            dd[i + 1] -= fact * du[i];
            du2[i] = 0.0;
        } else {
            pv[i] = 1.f;
            double fact = dd[i] / dl[i];
            dd[i] = dl[i];
            dl[i] = fact;
            double temp = du[i];
            du[i] = dd[i + 1];
            dd[i + 1] = temp - fact * dd[i + 1];
            if (i < NN - 2) { du2[i] = du[i + 1]; du[i + 1] = -fact * du[i + 1]; }
            else du2[i] = 0.0;
        }
    }
    for (int i = 0; i < NN; ++i)
        if (fabs(dd[i]) < 1e-300) dd[i] = (dd[i] < 0.0) ? -1e-300 : 1e-300;

    for (int i = 0; i < NN; ++i) {
        uint32_t h = ((uint32_t)i * 2654435761u) ^ ((uint32_t)p * 40503u);
        h = h * 1664525u + 1013904223u;
        X[i] = 1.0 + 1e-3 * ((double)(h & 2047) / 1024.0 - 1.0);
    }
    for (int iter = 0; iter < 2; ++iter) {
        for (int i = 0; i < NN - 1; ++i) {
            if (pv[i] == 0.f) X[i + 1] -= dl[i] * X[i];
            else { double t = X[i]; X[i] = X[i + 1]; X[i + 1] = t - dl[i] * X[i]; }
        }
        X[NN - 1] /= dd[NN - 1];
        X[NN - 2] = (X[NN - 2] - du[NN - 2] * X[NN - 1]) / dd[NN - 2];
        for (int i = NN - 3; i >= 0; --i)
            X[i] = (X[i] - du[i] * X[i + 1] - du2[i] * X[i + 2]) / dd[i];
        double nrm = 0.0;
        for (int i = 0; i < NN; ++i) nrm += X[i] * X[i];
        double inv = 1.0 / sqrt(fmax(nrm, 1e-300));
        for (int i = 0; i < NN; ++i) X[i] *= inv;
    }
    float* vt = vtri + (int64_t)p * NN;
    for (int i = 0; i < NN; ++i) vt[i] = (float)X[i];
}

// ---------------------------------------------------------------------------
__global__ void k_gs(float* vtri) {
    int b = blockIdx.x;
    float* V = vtri + (int64_t)b * NLOW * NN;
    __shared__ double red[256];
    for (int j = 0; j < NLOW; ++j) {
        float* vj = V + j * NN;
        for (int i2 = 0; i2 < j; ++i2) {
            const float* vi = V + i2 * NN;
            double acc = 0.0;
            for (int t = threadIdx.x; t < NN; t += 256) acc += (double)vi[t] * (double)vj[t];
            red[threadIdx.x] = acc; __syncthreads();
            for (int s = 128; s > 0; s >>= 1) {
                if ((int)threadIdx.x < s) red[threadIdx.x] += red[threadIdx.x + s];
                __syncthreads();
            }
            float r = (float)red[0];
            for (int t = threadIdx.x; t < NN; t += 256) vj[t] -= r * vi[t];
            __syncthreads();
        }
        double acc = 0.0;
        for (int t = threadIdx.x; t < NN; t += 256) acc += (double)vj[t] * (double)vj[t];
        red[threadIdx.x] = acc; __syncthreads();
        for (int s = 128; s > 0; s >>= 1) {
            if ((int)threadIdx.x < s) red[threadIdx.x] += red[threadIdx.x + s];
            __syncthreads();
        }
        float inv = (float)(1.0 / sqrt(fmax(red[0], 1e-300)));
        for (int t = threadIdx.x; t < NN; t += 256) vj[t] *= inv;
        __syncthreads();
    }
}

// ---------------------------------------------------------------------------
// Back-transform: H_k = I - taut_k * u_k u_k^T, applied k = NN-3 .. 0.
// Reflectors read coalesced from Urev rows when available, else strided from M.
__global__ __launch_bounds__(512) void k_backtransform(const float* M, const float* Urev,
                                                       int useU, const float* tauA,
                                                       const float* vtri, float* out) {
    int b = blockIdx.x;
    int pass = blockIdx.y;
    int w = threadIdx.x >> 6;
    int lane = threadIdx.x & 63;
    int j = pass * 8 + w;
    __shared__ float xs[8][NN];
    __shared__ float us[NN];
    const float* Mb = M + (int64_t)b * NN * NN;
    for (int i = lane; i < NN; i += 64)
        xs[w][i] = vtri[((int64_t)b * NLOW + j) * NN + i];
    __syncthreads();
    for (int k = NN - 3; k >= 0; --k) {
        int m = NN - 1 - k;
        if (useU) {
            const float* ur = Urev + ((int64_t)b * NN + k) * NN;
            for (int t = threadIdx.x; t < (unsigned)m; t += 512) us[t] = ur[t];
        } else {
            for (int t = threadIdx.x; t < (unsigned)m; t += 512)
                us[t] = Mb[(int64_t)(k + 1 + t) * NN + k];
        }
        __syncthreads();
        float tauk = tauA[b * NN + k];
        float acc = 0.f;
        for (int t = lane; t < m; t += 64) acc += us[t] * xs[w][k + 1 + t];
        for (int off = 32; off > 0; off >>= 1) acc += __shfl_xor(acc, off);
        float s = tauk * acc;
        for (int t = lane; t < m; t += 64) xs[w][k + 1 + t] -= s * us[t];
        __syncthreads();
    }
    float mx = -1.f; int mi = 0;
    for (int i = lane; i < NN; i += 64) {
        float a = fabsf(xs[w][i]);
        if (a > mx) { mx = a; mi = i; }
    }
    for (int off = 32; off > 0; off >>= 1) {
        float omx = __shfl_xor(mx, off);
        int omi = __shfl_xor(mi, off);
        if (omx > mx || (omx == mx && omi < mi)) { mx = omx; mi = omi; }
    }
    float sgn = (xs[w][mi] < 0.f) ? -1.f : 1.f;
    for (int i = lane; i < NN; i += 64)
        out[256 + ((int64_t)(b * NN + i)) * NLOW + j] = sgn * xs[w][i];
}

// ---------------------------------------------------------------------------
extern "C" void kernel_launch(void* const* d_in, const int* in_sizes, int n_in,
                              void* d_out, int out_size, void* d_ws, size_t ws_size,
                              hipStream_t stream) {
    const float* A = (const float*)d_in[0];
    float* out = (float*)d_out;

    char* base = (char*)d_ws;
    size_t off = 0;
    auto alloc = [&](size_t bytes) -> void* {
        void* p = (void*)(base + off);
        off = (off + bytes + 255) & ~(size_t)255;
        return p;
    };
    double* lam  = (double*)alloc(sizeof(double) * NB * NLOW);
    double* u0   = (double*)alloc(sizeof(double) * (size_t)NB * NLOW * NN);
    double* u1   = (double*)alloc(sizeof(double) * (size_t)NB * NLOW * NN);
    double* u2   = (double*)alloc(sizeof(double) * (size_t)NB * NLOW * NN);
    double* lmul = (double*)alloc(sizeof(double) * (size_t)NB * NLOW * NN);
    double* xv   = (double*)alloc(sizeof(double) * (size_t)NB * NLOW * NN);
    float* pivf  = (float*)alloc(sizeof(float) * (size_t)NB * NLOW * NN);
    float* vtri  = (float*)alloc(sizeof(float) * (size_t)NB * NLOW * NN);
    float* tau   = (float*)alloc(sizeof(float) * NB * NN);
    float* evec  = (float*)alloc(sizeof(float) * NB * NN);
    float* dvec  = (float*)alloc(sizeof(float) * NB * NN);
    float* wv    = (float*)alloc(sizeof(float) * NB * NN);
    double* dotwA = (double*)alloc(sizeof(double) * NB * NN);
    double* c1A   = (double*)alloc(sizeof(double) * NB * PNB);
    double* c2A   = (double*)alloc(sizeof(double) * NB * PNB);
    float* Vp    = (float*)alloc(sizeof(float) * (size_t)NB * PNB * NN);
    float* Wp    = (float*)alloc(sizeof(float) * (size_t)NB * PNB * NN);
    size_t small_end = off;
    size_t mat_bytes = sizeof(float) * (size_t)NB * NN * NN;

    float* M;
    if (ws_size >= small_end + mat_bytes)
        M = (float*)alloc(mat_bytes);
    else
        M = (float*)d_in[0];   // in-place fallback (harness restores d_in)

    float* Urev = nullptr;
    int useU = 0;
    if (ws_size >= off + mat_bytes) {
        Urev = (float*)alloc(mat_bytes);
        useU = 1;
    }

    int grid_sym = (NB * NN * NN) / 256;
    k_symmetrize<<<grid_sym, 256, 0, stream>>>(A, M);
    k_zeroinit<<<(NB * NN + 255) / 256, 256, 0, stream>>>(wv);

    for (int k0 = 0; k0 < NN - 2; k0 += PNB) {
        int jmax = NN - 2 - k0; if (jmax > PNB) jmax = PNB;
        for (int j = 0; j < jmax; ++j) {
            k_mid<<<NB, 1024, 0, stream>>>(M, Vp, Wp, wv, tau, evec, dvec,
                                           dotwA, c1A, c2A, Urev, useU, k0, j, 1);
            int k = k0 + j, m = NN - 1 - k;
            int nr = (m + 255) / 256, nc = (m + JCH - 1) / JCH;
            k_symv<<<dim3(NB, nr, nc), 256, 0, stream>>>(M, Vp, wv, k0, j);
        }
        k_mid<<<NB, 1024, 0, stream>>>(M, Vp, Wp, wv, tau, evec, dvec,
                                       dotwA, c1A, c2A, Urev, useU, k0, jmax, 0);
        int s = k0 + jmax, m2 = NN - s;
        if (m2 > 0) {
            dim3 gu(NB, (unsigned)((m2 + 63) / 64), (unsigned)((m2 + 63) / 64));
            k_update<<<gu, 256, 0, stream>>>(M, Vp, Wp, tau, dotwA, k0, jmax);
        }
    }

    k_extract2<<<NB, 64, 0, stream>>>(M, dvec, evec);
    k_bisect<<<1, 256, 0, stream>>>(dvec, evec, lam, out);
    k_invit<<<4, 64, 0, stream>>>(dvec, evec, lam, vtri, u0, u1, u2, lmul, pivf, xv);
    k_gs<<<NB, 256, 0, stream>>>(vtri);
    dim3 gI(NB, 2);
    k_backtransform<<<gI, 512, 0, stream>>>(M, Urev, useU, tau, vtri, out);
}